// Round 11
// baseline (257.826 us; speedup 1.0000x reference)
//
#include <hip/hip_runtime.h>
#include <math.h>

typedef unsigned short u16;
typedef unsigned int u32;
typedef __attribute__((ext_vector_type(8))) _Float16 half8;   // fp16x8
typedef __attribute__((ext_vector_type(2))) _Float16 half2v;  // fp16x2
typedef __attribute__((ext_vector_type(8))) u16 ushort8;
typedef __attribute__((ext_vector_type(4))) float f32x4;

__device__ __forceinline__ u16 f2h(float f) {
    union { u16 u; _Float16 h; } c; c.h = (_Float16)f; return c.u;
}

#if __has_builtin(__builtin_amdgcn_fdot2)
#define FDOT2(a, b, c) __builtin_amdgcn_fdot2((a), (b), (c), false)
#else
#define FDOT2(a, b, c) fmaf((float)(a)[0], (float)(b)[0], \
                        fmaf((float)(a)[1], (float)(b)[1], (c)))
#endif

// async global(16B) -> LDS, per-lane source addr, wave-linear LDS dest
__device__ __forceinline__ void gload16(void* lds, const void* g) {
    __builtin_amdgcn_global_load_lds(
        (const __attribute__((address_space(1))) u32*)g,
        (__attribute__((address_space(3))) u32*)lds,
        16, 0, 0);
}

// ---------------------------------------------------------------------------
// GEMM body: C[M,512] = A[M,512](fp16) @ Bt[512,512](fp16,[n][k]) + bias.
//
// Depth-2 counted-vmcnt pipeline, 3 LDS buffers (48 KB -> 3 blocks/CU):
// per k-step:  vmcnt(4)  (tile kt's own 4 loads done; kt+1 stays in flight)
//              s_barrier + sched_barrier(0)
//              STAGE(kt+2)   (safe: all waves passed barrier after reading
//                             this buffer's previous tile at iter kt-1)
//              COMPUTE(kt)
// Tile kt staged 2 iterations ahead of its wait -> ~600+ cyc of latency
// hidden. vmcnt never drains to 0 mid-loop (tail: kt=15 -> vmcnt(0)).
//
// LDS tile [128][32]u16, XOR slot-swizzle (verified r6: bank conflicts -> 0):
// linear gload_lds dest + inverse-swizzled GLOBAL source col + swizzled read.
// ---------------------------------------------------------------------------
template <int OUTMODE>   // 0: f32 store, 1: fp16 store
__device__ __forceinline__ void gemm_body(
    const u16* A, const u16* Bt, const float* bias, void* Cout, int Mout,
    int m0, int n0, u16* AsB, u16* BsB)
{
    const int tid  = threadIdx.x;
    const int wave = tid >> 6;
    const int lane = tid & 63;
    const int wr = (wave >> 1) * 64;
    const int wc = (wave & 1) * 64;

    f32x4 acc[4][4];
#pragma unroll
    for (int i = 0; i < 4; ++i)
#pragma unroll
        for (int j = 0; j < 4; ++j) acc[i][j] = (f32x4){0.f, 0.f, 0.f, 0.f};

    const int srow  = lane >> 2;                              // 0..15
    const int scolG = ((lane & 3) ^ ((srow >> 1) & 3)) * 8;   // swizzled global col
    const size_t gOffA = (size_t)(m0 + wave * 32 + srow) * 512 + scolG;
    const size_t gOffB = (size_t)(n0 + wave * 32 + srow) * 512 + scolG;
    const int lOff = wave * 1024 + srow * 32 + (lane & 3) * 8;  // linear dest

    const int fR = ((lane & 15) >> 1) & 3;
    const int paOff = (wr + (lane & 15)) * 32 + ((lane >> 4) ^ fR) * 8;
    const int pbOff = (wc + (lane & 15)) * 32 + ((lane >> 4) ^ fR) * 8;

    auto STAGE = [&](int buf, int ko) {
        u16* sa = AsB + buf * 4096;
        u16* sb = BsB + buf * 4096;
        gload16(sa + lOff,       A  + gOffA + ko);
        gload16(sa + lOff + 512, A  + gOffA + ko + 16 * 512);
        gload16(sb + lOff,       Bt + gOffB + ko);
        gload16(sb + lOff + 512, Bt + gOffB + ko + 16 * 512);
    };
    auto COMPUTE = [&](int buf) {
        const u16* sa = AsB + buf * 4096;
        const u16* sb = BsB + buf * 4096;
        half8 af[4], bf[4];
#pragma unroll
        for (int i = 0; i < 4; ++i) af[i] = *(const half8*)(sa + paOff + i * 512);
#pragma unroll
        for (int j = 0; j < 4; ++j) bf[j] = *(const half8*)(sb + pbOff + j * 512);
#pragma unroll
        for (int i = 0; i < 4; ++i)
#pragma unroll
            for (int j = 0; j < 4; ++j)
                acc[i][j] = __builtin_amdgcn_mfma_f32_16x16x32_f16(
                    af[i], bf[j], acc[i][j], 0, 0, 0);
    };

    // prologue: 2 tiles in flight before first compute
    STAGE(0, 0);
    STAGE(1, 32);
#pragma unroll
    for (int kt = 0; kt < 16; ++kt) {
        // wait for tile kt only (its 4 loads are the oldest outstanding)
        if (kt < 15) asm volatile("s_waitcnt vmcnt(4)" ::: "memory");
        else         asm volatile("s_waitcnt vmcnt(0)" ::: "memory");
        __builtin_amdgcn_s_barrier();
        __builtin_amdgcn_sched_barrier(0);   // pin: no motion across barrier
        if (kt + 2 < 16) STAGE((kt + 2) % 3, (kt + 2) * 32);
        COMPUTE(kt % 3);
    }

    const int ccol  = n0 + wc + (lane & 15);
    const int crow0 = m0 + wr + (lane >> 4) * 4;
#pragma unroll
    for (int j = 0; j < 4; ++j) {
        const float b = bias[ccol + j * 16];
#pragma unroll
        for (int i = 0; i < 4; ++i) {
#pragma unroll
            for (int r = 0; r < 4; ++r) {
                int row = crow0 + i * 16 + r;
                if (row < Mout) {
                    float v = acc[i][j][r] + b;
                    size_t off = (size_t)row * 512 + ccol + j * 16;
                    if (OUTMODE == 0) ((float*)Cout)[off] = v;
                    else              ((u16*)Cout)[off] = f2h(v);
                }
            }
        }
    }
}

// Q and K projections in ONE dispatch: blockIdx.z selects output.
// Grid is (N-tiles=4, M-tiles, 2): consecutive blocks share the A M-tile
// (L2 reuse), and each N-tile's B panel stays L2-hot across all M-blocks.
__global__ __launch_bounds__(256) void gemm_qk(
    const u16* __restrict__ hh, const u16* __restrict__ Wqt,
    const u16* __restrict__ Wkt, const float* __restrict__ bqp,
    const float* __restrict__ bkp, u16* __restrict__ Qh,
    u16* __restrict__ Kb, int nPad)
{
    __shared__ __align__(16) u16 AsB[3 * 4096], BsB[3 * 4096];
    const u16* Bt = blockIdx.z ? Wkt : Wqt;
    const float* bias = blockIdx.z ? bkp : bqp;
    u16* out = blockIdx.z ? Kb : Qh;
    gemm_body<1>(hh, Bt, bias, out, nPad, blockIdx.y * 128, blockIdx.x * 128,
                 AsB, BsB);
}

__global__ __launch_bounds__(256) void gemm_wo(
    const u16* __restrict__ A, const u16* __restrict__ Wot,
    const float* __restrict__ bo, float* __restrict__ C, int Mout)
{
    __shared__ __align__(16) u16 AsB[3 * 4096], BsB[3 * 4096];
    gemm_body<0>(A, Wot, bo, C, Mout, blockIdx.y * 128, blockIdx.x * 128,
                 AsB, BsB);
}

// ---------------------------------------------------------------------------
// prep: fused conv_h (h f32 -> fp16, pad zeroed) + hist + conv_w.
// Grid partition: [0,nbH) conv_h, [nbH,nbH+nbE) hist, [nbH+nbE,+192) conv_w.
// ---------------------------------------------------------------------------
__global__ __launch_bounds__(256) void prep(
    const float* __restrict__ h, u16* __restrict__ hh, int nN,
    const int* __restrict__ rows, int* __restrict__ deg, int E,
    const float* __restrict__ Wq, const float* __restrict__ Wk,
    const float* __restrict__ Wo, const float* __restrict__ bq,
    const float* __restrict__ bk,
    u16* __restrict__ Wqt, u16* __restrict__ Wkt, u16* __restrict__ Wot,
    float* __restrict__ bqp, float* __restrict__ bkp,
    int nbH, int nbE)
{
    __shared__ float T[64][65];
    const int tid = threadIdx.x;
    const int b = blockIdx.x;

    if (b < nbH) {
        // ---- conv_h ----
        int t = b * 256 + tid;
        size_t e = (size_t)t * 8;
        int row = (int)(e >> 9);
        ushort8 o;
        if (row < nN) {
            f32x4 a = *(const f32x4*)(h + e);
            f32x4 bb = *(const f32x4*)(h + e + 4);
            float x[8] = {a.x, a.y, a.z, a.w, bb.x, bb.y, bb.z, bb.w};
#pragma unroll
            for (int i = 0; i < 8; ++i) o[i] = f2h(x[i]);
        } else {
            o = (ushort8){0,0,0,0,0,0,0,0};
        }
        *(ushort8*)(hh + e) = o;
        return;
    }
    if (b < nbH + nbE) {
        // ---- hist ----
        int i = (b - nbH) * 256 + tid;
        if (i < E) atomicAdd(&deg[rows[i]], 1);
        return;
    }
    // ---- conv_w ----  (192 blocks: z = rem>>6, by = (rem&63)>>3, bx = rem&7)
    int rem = b - nbH - nbE;
    const int z = rem >> 6;
    const int X = (rem & 7) * 64;
    const int Y = ((rem >> 3) & 7) * 64;

    const int r4 = tid >> 4;
    const int c4 = (tid & 15) * 4;
    if (z < 2) {
        const float* W = z ? Wk : Wq;
#pragma unroll
        for (int rr = 0; rr < 64; rr += 16) {
            f32x4 v = *(const f32x4*)(W + (size_t)(X + rr + r4) * 512 + Y + c4);
            T[rr + r4][c4 + 0] = v.x; T[rr + r4][c4 + 1] = v.y;
            T[rr + r4][c4 + 2] = v.z; T[rr + r4][c4 + 3] = v.w;
        }
    } else {
#pragma unroll
        for (int rr = 0; rr < 64; rr += 16) {
            int p2 = (rr + r4) * 8 + (X >> 6);   // perm(X + rr + r4)
            f32x4 v = *(const f32x4*)(Wo + (size_t)p2 * 512 + Y + c4);
            T[rr + r4][c4 + 0] = v.x; T[rr + r4][c4 + 1] = v.y;
            T[rr + r4][c4 + 2] = v.z; T[rr + r4][c4 + 3] = v.w;
        }
    }
    __syncthreads();

    const int cc = tid >> 2;
    const int ks = (tid & 3) * 16;
    const int pc = Y + cc;
    const int ro = (z < 2) ? ((pc & 7) * 64 + (pc >> 3)) : pc;
    ushort8 h0, h1;
#pragma unroll
    for (int t = 0; t < 8; ++t) {
        h0[t] = f2h(T[ks + t][cc]);
        h1[t] = f2h(T[ks + 8 + t][cc]);
    }
    size_t o = (size_t)ro * 512 + X + ks;
    if (z == 0) {
        *(ushort8*)(Wqt + o) = h0; *(ushort8*)(Wqt + o + 8) = h1;
    } else if (z == 1) {
        *(ushort8*)(Wkt + o) = h0; *(ushort8*)(Wkt + o + 8) = h1;
    } else {
        *(ushort8*)(Wot + o) = h0; *(ushort8*)(Wot + o + 8) = h1;
        if (rem == 128) {   // z==2, bx==0, by==0
            for (int bi = tid; bi < 512; bi += 256) {
                int pp = (bi & 63) * 8 + (bi >> 6);
                bqp[bi] = bq[pp];
                bkp[bi] = bk[pp];
            }
        }
    }
}

// ---------------------------------------------------------------------------
// CSR scan: partial sums (13 blocks) -> final (13 blocks, self-scans bsum)
// ---------------------------------------------------------------------------
#define SCAN_CHUNK 2048

__global__ __launch_bounds__(256) void scan_partial(
    const int* __restrict__ deg, int* __restrict__ bsum, int n)
{
    int base = blockIdx.x * SCAN_CHUNK;
    int t = threadIdx.x;
    int s = 0;
    for (int i = t; i < SCAN_CHUNK; i += 256) {
        int g = base + i;
        s += (g < n) ? deg[g] : 0;
    }
#pragma unroll
    for (int off = 1; off < 64; off <<= 1) s += __shfl_xor(s, off, 64);
    __shared__ int ws[4];
    if ((t & 63) == 0) ws[t >> 6] = s;
    __syncthreads();
    if (t == 0) bsum[blockIdx.x] = ws[0] + ws[1] + ws[2] + ws[3];
}

__global__ __launch_bounds__(256) void scan_final(
    const int* __restrict__ deg, const int* __restrict__ bsum,
    int* __restrict__ rowptr, int* __restrict__ cursor, int n, int nb)
{
    // every block redundantly scans the nb block sums (broadcast loads)
    int boff = 0, total = 0;
    for (int i = 0; i < nb; ++i) {
        int v = bsum[i];
        if (i < (int)blockIdx.x) boff += v;
        total += v;
    }
    int t = threadIdx.x;
    int base = blockIdx.x * SCAN_CHUNK + t * 8;
    int v[8];
    int s = 0;
#pragma unroll
    for (int i = 0; i < 8; ++i) {
        int g = base + i;
        v[i] = (g < n) ? deg[g] : 0;
        s += v[i];
    }
    int lane = t & 63, w = t >> 6;
    int inc = s;
#pragma unroll
    for (int off = 1; off < 64; off <<= 1) {
        int x = __shfl_up(inc, off, 64);
        if (lane >= off) inc += x;
    }
    __shared__ int wsum[4];
    if (lane == 63) wsum[w] = inc;
    __syncthreads();
    int excl = boff + inc - s;
    for (int i = 0; i < w; ++i) excl += wsum[i];
#pragma unroll
    for (int i = 0; i < 8; ++i) {
        int g = base + i;
        if (g < n) { rowptr[g] = excl; cursor[g] = excl; }
        excl += v[i];
    }
    if (blockIdx.x == 0 && t == 0) rowptr[n] = total;
}

__global__ void scatter_kernel(const int* __restrict__ rows, const int* __restrict__ cols,
                               int* __restrict__ cursor, int* __restrict__ colc, int E)
{
    int i = blockIdx.x * 256 + threadIdx.x;
    if (i < E) {
        int pos = atomicAdd(&cursor[rows[i]], 1);
        colc[pos] = cols[i];
    }
}

// ---------------------------------------------------------------------------
// Fused SDDMM + online segment softmax + SpMM. Head-major layout:
// lane l -> head l>>3, dims (l&7)*8..+7. One wave per node, 4 nodes/block.
// 4-edge unroll + depth-4 prefetch. Packed fp16 math: scores via
// v_dot2_f32_f16 (f32 accumulate), aggregation via packed fp16 FMA (fp16 acc,
// defer-max THR=4 so w <= e^4: den <= deg*54.6, acc far from fp16 overflow).
// v == k (source bug): K row loaded for the dot is reused for aggregation.
// ---------------------------------------------------------------------------
__global__ __launch_bounds__(256) void node_agg(
    const u16* __restrict__ Qh, const u16* __restrict__ Kb,
    const int* __restrict__ rowptr, const int* __restrict__ colc,
    u16* __restrict__ aggb, int nN)
{
    int node = blockIdx.x * 4 + (threadIdx.x >> 6);
    int lane = threadIdx.x & 63;
    if (node >= nN) return;
    size_t base = (size_t)node * 512 + lane * 8;

    half8 qv = __builtin_nontemporal_load((const half8*)(Qh + base));
    half2v q2[4];
#pragma unroll
    for (int i = 0; i < 4; ++i) q2[i] = (half2v){qv[2 * i], qv[2 * i + 1]};

    int start = rowptr[node];
    int deg   = rowptr[node + 1] - start;
    const int* cp = colc + start;
    const size_t loff = (size_t)lane * 8;

    float m = -__builtin_inff();
    float den = 0.f;
    half2v acc2[4];
#pragma unroll
    for (int i = 0; i < 4; ++i) acc2[i] = (half2v){(_Float16)0.f, (_Float16)0.f};

    if (deg > 0) {
        const int dl = deg - 1;
        half8 k0 = *(const half8*)(Kb + (size_t)cp[0] * 512 + loff);
        half8 k1 = *(const half8*)(Kb + (size_t)cp[1 < dl ? 1 : dl] * 512 + loff);
        half8 k2 = *(const half8*)(Kb + (size_t)cp[2 < dl ? 2 : dl] * 512 + loff);
        half8 k3 = *(const half8*)(Kb + (size_t)cp[3 < dl ? 3 : dl] * 512 + loff);
        for (int j = 0; j < deg; j += 4) {
            int i4 = j + 4 < dl ? j + 4 : dl;
            int i5 = j + 5 < dl ? j + 5 : dl;
            int i6 = j + 6 < dl ? j + 6 : dl;
            int i7 = j + 7 < dl ? j + 7 : dl;
            half8 n0 = *(const half8*)(Kb + (size_t)cp[i4] * 512 + loff);
            half8 n1 = *(const half8*)(Kb + (size_t)cp[i5] * 512 + loff);
            half8 n2 = *(const half8*)(Kb + (size_t)cp[i6] * 512 + loff);
            half8 n3 = *(const half8*)(Kb + (size_t)cp[i7] * 512 + loff);

            float p0 = 0.f, p1 = 0.f, p2 = 0.f, p3 = 0.f;
#pragma unroll
            for (int i = 0; i < 4; ++i) {
                half2v a = q2[i];
                half2v b0 = (half2v){k0[2 * i], k0[2 * i + 1]};
                half2v b1 = (half2v){k1[2 * i], k1[2 * i + 1]};
                half2v b2 = (half2v){k2[2 * i], k2[2 * i + 1]};
                half2v b3 = (half2v){k3[2 * i], k3[2 * i + 1]};
                p0 = FDOT2(a, b0, p0);
                p1 = FDOT2(a, b1, p1);
                p2 = FDOT2(a, b2, p2);
                p3 = FDOT2(a, b3, p3);
            }
#pragma unroll
            for (int off = 1; off < 8; off <<= 1) {
                p0 += __shfl_xor(p0, off, 64);
                p1 += __shfl_xor(p1, off, 64);
                p2 += __shfl_xor(p2, off, 64);
                p3 += __shfl_xor(p3, off, 64);
            }

            // defer-max (THR=4, fp16-acc-safe): one check per 4-edge group
            float pm = fmaxf(fmaxf(p0, p1), fmaxf(p2, p3));
            if (__any(pm > m + 4.f)) {
                float mn = fmaxf(m, pm);
                float sc = __expf(m - mn);   // first group: exp(-inf)=0
                den *= sc;
                _Float16 sch = (_Float16)sc;
                half2v sc2 = {sch, sch};
#pragma unroll
                for (int i = 0; i < 4; ++i) acc2[i] *= sc2;
                m = mn;
            }
            float w0 = __expf(p0 - m);       // each bounded by e^4
            float w1 = (j + 1 < deg) ? __expf(p1 - m) : 0.f;
            float w2 = (j + 2 < deg) ? __expf(p2 - m) : 0.f;
            float w3 = (j + 3 < deg) ? __expf(p3 - m) : 0.f;
            den += (w0 + w1) + (w2 + w3);
            _Float16 h0 = (_Float16)w0, h1 = (_Float16)w1;
            _Float16 h2 = (_Float16)w2, h3 = (_Float16)w3;
            half2v w02 = {h0, h0}, w12 = {h1, h1}, w22 = {h2, h2}, w32 = {h3, h3};
#pragma unroll
            for (int i = 0; i < 4; ++i) {
                half2v b0 = (half2v){k0[2 * i], k0[2 * i + 1]};
                half2v b1 = (half2v){k1[2 * i], k1[2 * i + 1]};
                half2v b2 = (half2v){k2[2 * i], k2[2 * i + 1]};
                half2v b3 = (half2v){k3[2 * i], k3[2 * i + 1]};
                acc2[i] += w02 * b0;
                acc2[i] += w12 * b1;
                acc2[i] += w22 * b2;
                acc2[i] += w32 * b3;
            }
            k0 = n0; k1 = n1; k2 = n2; k3 = n3;
        }
    }

    float inv = (deg > 0) ? 1.f / den : 0.f;
    ushort8 o;
#pragma unroll
    for (int i = 0; i < 4; ++i) {
        o[2 * i]     = f2h((float)acc2[i][0] * inv);
        o[2 * i + 1] = f2h((float)acc2[i][1] * inv);
    }
    __builtin_nontemporal_store(o, (ushort8*)(aggb + base));
}

// ---------------------------------------------------------------------------
extern "C" void kernel_launch(void* const* d_in, const int* in_sizes, int n_in,
                              void* d_out, int out_size, void* d_ws, size_t ws_size,
                              hipStream_t stream)
{
    const float* h  = (const float*)d_in[0];
    const float* Wq = (const float*)d_in[1];
    const float* bq = (const float*)d_in[2];
    const float* Wk = (const float*)d_in[3];
    const float* bk = (const float*)d_in[4];
    const float* Wo = (const float*)d_in[5];
    const float* bo = (const float*)d_in[6];
    const int* rows = (const int*)d_in[7];
    const int* cols = (const int*)d_in[8];
    float* out = (float*)d_out;

    const int HID = 512;
    const int nN  = in_sizes[0] / HID;              // 25000
    const int E   = in_sizes[7];                    // 400000
    const int nPad = (nN + 127) & ~127;             // 25088
    const int nb = (nN + SCAN_CHUNK - 1) / SCAN_CHUNK;  // 13
    const int nbH = nPad * (HID / 8) / 256;         // conv_h blocks: 6272
    const int nbE = (E + 255) / 256;                // hist blocks: 1563

    // workspace layout (all 16B-aligned), fp16 throughout (~81 MB)
    char* w = (char*)d_ws;
    u16* Kb  = (u16*)w;  w += (size_t)nPad * HID * 2;  // 25.7 MB
    u16* hh  = (u16*)w;  w += (size_t)nPad * HID * 2;  // 25.7 MB (reused as agg)
    u16* Qh  = (u16*)w;  w += (size_t)nPad * HID * 2;  // 25.7 MB
    u16* Wqt = (u16*)w;  w += 512 * 512 * 2;
    u16* Wkt = (u16*)w;  w += 512 * 512 * 2;
    u16* Wot = (u16*)w;  w += 512 * 512 * 2;
    float* bqp = (float*)w;  w += 512 * 4;
    float* bkp = (float*)w;  w += 512 * 4;
    int* rowptr = (int*)w;   w += (size_t)(nN + 1) * 4;
    int* cursor = (int*)w;   w += (size_t)nN * 4;
    int* deg    = (int*)w;   w += (size_t)nN * 4;
    int* bsum   = (int*)w;   w += 64 * 4;
    int* colc   = (int*)w;   /* E*4 */

    (void)hipMemsetAsync(deg, 0, (size_t)nN * sizeof(int), stream);

    // fused conv_h + hist + conv_w
    prep<<<nbH + nbE + 192, 256, 0, stream>>>(
        h, hh, nN, rows, deg, E, Wq, Wk, Wo, bq, bk,
        Wqt, Wkt, Wot, bqp, bkp, nbH, nbE);

    // CSR: partial scan -> final scan (self-scans block sums) -> scatter
    scan_partial<<<nb, 256, 0, stream>>>(deg, bsum, nN);
    scan_final<<<nb, 256, 0, stream>>>(deg, bsum, rowptr, cursor, nN, nb);
    scatter_kernel<<<(E + 255) / 256, 256, 0, stream>>>(rows, cols, cursor, colc, E);

    // Q + K projections in one dispatch (head-major outputs, fp16)
    // grid: (N-tiles, M-tiles, {Q,K}) — consecutive blocks share the A tile
    gemm_qk<<<dim3(4, nPad / 128, 2), 256, 0, stream>>>(
        hh, Wqt, Wkt, bqp, bkp, Qh, Kb, nPad);

    // fused SDDMM + softmax + aggregate -> fp16 agg (overwrites hh)
    node_agg<<<(nN + 3) / 4, 256, 0, stream>>>(Qh, Kb, rowptr, colc, hh, nN);

    // output projection -> f32 out
    gemm_wo<<<dim3(4, nPad / 128), 256, 0, stream>>>(hh, Wot, bo, out, nN);
}

// Round 12
// 235.310 us; speedup vs baseline: 1.0957x; 1.0957x over previous
//
#include <hip/hip_runtime.h>
#include <math.h>

typedef unsigned short u16;
typedef unsigned int u32;
typedef __attribute__((ext_vector_type(8))) _Float16 half8;   // fp16x8
typedef __attribute__((ext_vector_type(2))) _Float16 half2v;  // fp16x2
typedef __attribute__((ext_vector_type(8))) u16 ushort8;
typedef __attribute__((ext_vector_type(4))) float f32x4;

__device__ __forceinline__ u16 f2h(float f) {
    union { u16 u; _Float16 h; } c; c.h = (_Float16)f; return c.u;
}

#if __has_builtin(__builtin_amdgcn_fdot2)
#define FDOT2(a, b, c) __builtin_amdgcn_fdot2((a), (b), (c), false)
#else
#define FDOT2(a, b, c) fmaf((float)(a)[0], (float)(b)[0], \
                        fmaf((float)(a)[1], (float)(b)[1], (c)))
#endif

// async global(16B) -> LDS, per-lane source addr, wave-linear LDS dest
__device__ __forceinline__ void gload16(void* lds, const void* g) {
    __builtin_amdgcn_global_load_lds(
        (const __attribute__((address_space(1))) u32*)g,
        (__attribute__((address_space(3))) u32*)lds,
        16, 0, 0);
}

// ---------------------------------------------------------------------------
// GEMM body: C[M,512] = A[M,512](fp16) @ Bt[512,512](fp16,[n][k]) + bias.
// Round-9 proven structure: 2-phase double-buffer, 32 KB LDS, one
// __syncthreads per k-step, STAGE(next) issued before COMPUTE(current).
// LDS tile [128][32]u16, XOR slot-swizzle (verified r6: bank conflicts -> 0).
// ---------------------------------------------------------------------------
template <int OUTMODE>   // 0: f32 store, 1: fp16 store
__device__ __forceinline__ void gemm_body(
    const u16* A, const u16* Bt, const float* bias, void* Cout, int Mout,
    int m0, int n0, u16* As0, u16* As1, u16* Bs0, u16* Bs1)
{
    const int tid  = threadIdx.x;
    const int wave = tid >> 6;
    const int lane = tid & 63;
    const int wr = (wave >> 1) * 64;
    const int wc = (wave & 1) * 64;

    f32x4 acc[4][4];
#pragma unroll
    for (int i = 0; i < 4; ++i)
#pragma unroll
        for (int j = 0; j < 4; ++j) acc[i][j] = (f32x4){0.f, 0.f, 0.f, 0.f};

    const int srow  = lane >> 2;                              // 0..15
    const int scolG = ((lane & 3) ^ ((srow >> 1) & 3)) * 8;   // swizzled global col
    const size_t gOffA = (size_t)(m0 + wave * 32 + srow) * 512 + scolG;
    const size_t gOffB = (size_t)(n0 + wave * 32 + srow) * 512 + scolG;
    const int lOff = wave * 1024 + srow * 32 + (lane & 3) * 8;  // linear dest

    const int fR = ((lane & 15) >> 1) & 3;
    const int paOff = (wr + (lane & 15)) * 32 + ((lane >> 4) ^ fR) * 8;
    const int pbOff = (wc + (lane & 15)) * 32 + ((lane >> 4) ^ fR) * 8;

    auto STAGE = [&](u16* sa, u16* sb, int ko) {
        gload16(sa + lOff,       A  + gOffA + ko);
        gload16(sa + lOff + 512, A  + gOffA + ko + 16 * 512);
        gload16(sb + lOff,       Bt + gOffB + ko);
        gload16(sb + lOff + 512, Bt + gOffB + ko + 16 * 512);
    };
    auto COMPUTE = [&](const u16* sa, const u16* sb) {
        half8 af[4], bf[4];
#pragma unroll
        for (int i = 0; i < 4; ++i) af[i] = *(const half8*)(sa + paOff + i * 512);
#pragma unroll
        for (int j = 0; j < 4; ++j) bf[j] = *(const half8*)(sb + pbOff + j * 512);
#pragma unroll
        for (int i = 0; i < 4; ++i)
#pragma unroll
            for (int j = 0; j < 4; ++j)
                acc[i][j] = __builtin_amdgcn_mfma_f32_16x16x32_f16(
                    af[i], bf[j], acc[i][j], 0, 0, 0);
    };

    STAGE(As0, Bs0, 0);
    __syncthreads();
#pragma unroll
    for (int kt = 0; kt < 16; kt += 2) {
        STAGE(As1, Bs1, (kt + 1) * 32);
        COMPUTE(As0, Bs0);
        __syncthreads();
        if (kt + 2 < 16) STAGE(As0, Bs0, (kt + 2) * 32);
        COMPUTE(As1, Bs1);
        __syncthreads();
    }

    const int ccol  = n0 + wc + (lane & 15);
    const int crow0 = m0 + wr + (lane >> 4) * 4;
#pragma unroll
    for (int j = 0; j < 4; ++j) {
        const float b = bias[ccol + j * 16];
#pragma unroll
        for (int i = 0; i < 4; ++i) {
#pragma unroll
            for (int r = 0; r < 4; ++r) {
                int row = crow0 + i * 16 + r;
                if (row < Mout) {
                    float v = acc[i][j][r] + b;
                    size_t off = (size_t)row * 512 + ccol + j * 16;
                    if (OUTMODE == 0) ((float*)Cout)[off] = v;
                    else              ((u16*)Cout)[off] = f2h(v);
                }
            }
        }
    }
}

// Q and K projections in ONE dispatch, XCD-grouped block mapping:
// the 8 blocks sharing an A M-tile (4 N-tiles x {Q,K}) get bids
// bid = 64*(m/8) + 8*s + (m%8)  =>  all 8 sharers have the same bid%8
// (same XCD under round-robin dispatch) and are adjacent in dispatch
// order (co-resident) -> A-tile read once from HBM, 7x from that XCD's L2.
__global__ __launch_bounds__(256) void gemm_qk(
    const u16* __restrict__ hh, const u16* __restrict__ Wqt,
    const u16* __restrict__ Wkt, const float* __restrict__ bqp,
    const float* __restrict__ bkp, u16* __restrict__ Qh,
    u16* __restrict__ Kb, int nPad)
{
    const int bid = blockIdx.x;
    const int m = (bid >> 6) * 8 + (bid & 7);
    const int s = (bid >> 3) & 7;
    if (m >= nPad / 128) return;
    const int z = s >> 2;        // 0: Q, 1: K
    const int n = s & 3;         // N-tile

    __shared__ __align__(16) u16 As0[4096], As1[4096], Bs0[4096], Bs1[4096];
    const u16* Bt = z ? Wkt : Wqt;
    const float* bias = z ? bkp : bqp;
    u16* out = z ? Kb : Qh;
    gemm_body<1>(hh, Bt, bias, out, nPad, m * 128, n * 128,
                 As0, As1, Bs0, Bs1);
}

// Wo projection, same XCD-grouping with 4 sharers per A M-tile:
// bid = 32*(m/8) + 8*s + (m%8), s in 0..3.
__global__ __launch_bounds__(256) void gemm_wo(
    const u16* __restrict__ A, const u16* __restrict__ Wot,
    const float* __restrict__ bo, float* __restrict__ C, int Mout, int nPad)
{
    const int bid = blockIdx.x;
    const int m = (bid >> 5) * 8 + (bid & 7);
    const int s = (bid >> 3) & 3;
    if (m >= nPad / 128) return;

    __shared__ __align__(16) u16 As0[4096], As1[4096], Bs0[4096], Bs1[4096];
    gemm_body<0>(A, Wot, bo, C, Mout, m * 128, s * 128,
                 As0, As1, Bs0, Bs1);
}

// ---------------------------------------------------------------------------
// prep: fused conv_h (h f32 -> fp16, pad zeroed) + hist + conv_w.
// Grid partition: [0,nbH) conv_h, [nbH,nbH+nbE) hist, [nbH+nbE,+192) conv_w.
// ---------------------------------------------------------------------------
__global__ __launch_bounds__(256) void prep(
    const float* __restrict__ h, u16* __restrict__ hh, int nN,
    const int* __restrict__ rows, int* __restrict__ deg, int E,
    const float* __restrict__ Wq, const float* __restrict__ Wk,
    const float* __restrict__ Wo, const float* __restrict__ bq,
    const float* __restrict__ bk,
    u16* __restrict__ Wqt, u16* __restrict__ Wkt, u16* __restrict__ Wot,
    float* __restrict__ bqp, float* __restrict__ bkp,
    int nbH, int nbE)
{
    __shared__ float T[64][65];
    const int tid = threadIdx.x;
    const int b = blockIdx.x;

    if (b < nbH) {
        // ---- conv_h ----
        int t = b * 256 + tid;
        size_t e = (size_t)t * 8;
        int row = (int)(e >> 9);
        ushort8 o;
        if (row < nN) {
            f32x4 a = *(const f32x4*)(h + e);
            f32x4 bb = *(const f32x4*)(h + e + 4);
            float x[8] = {a.x, a.y, a.z, a.w, bb.x, bb.y, bb.z, bb.w};
#pragma unroll
            for (int i = 0; i < 8; ++i) o[i] = f2h(x[i]);
        } else {
            o = (ushort8){0,0,0,0,0,0,0,0};
        }
        *(ushort8*)(hh + e) = o;
        return;
    }
    if (b < nbH + nbE) {
        // ---- hist ----
        int i = (b - nbH) * 256 + tid;
        if (i < E) atomicAdd(&deg[rows[i]], 1);
        return;
    }
    // ---- conv_w ----  (192 blocks: z = rem>>6, by = (rem&63)>>3, bx = rem&7)
    int rem = b - nbH - nbE;
    const int z = rem >> 6;
    const int X = (rem & 7) * 64;
    const int Y = ((rem >> 3) & 7) * 64;

    const int r4 = tid >> 4;
    const int c4 = (tid & 15) * 4;
    if (z < 2) {
        const float* W = z ? Wk : Wq;
#pragma unroll
        for (int rr = 0; rr < 64; rr += 16) {
            f32x4 v = *(const f32x4*)(W + (size_t)(X + rr + r4) * 512 + Y + c4);
            T[rr + r4][c4 + 0] = v.x; T[rr + r4][c4 + 1] = v.y;
            T[rr + r4][c4 + 2] = v.z; T[rr + r4][c4 + 3] = v.w;
        }
    } else {
#pragma unroll
        for (int rr = 0; rr < 64; rr += 16) {
            int p2 = (rr + r4) * 8 + (X >> 6);   // perm(X + rr + r4)
            f32x4 v = *(const f32x4*)(Wo + (size_t)p2 * 512 + Y + c4);
            T[rr + r4][c4 + 0] = v.x; T[rr + r4][c4 + 1] = v.y;
            T[rr + r4][c4 + 2] = v.z; T[rr + r4][c4 + 3] = v.w;
        }
    }
    __syncthreads();

    const int cc = tid >> 2;
    const int ks = (tid & 3) * 16;
    const int pc = Y + cc;
    const int ro = (z < 2) ? ((pc & 7) * 64 + (pc >> 3)) : pc;
    ushort8 h0, h1;
#pragma unroll
    for (int t = 0; t < 8; ++t) {
        h0[t] = f2h(T[ks + t][cc]);
        h1[t] = f2h(T[ks + 8 + t][cc]);
    }
    size_t o = (size_t)ro * 512 + X + ks;
    if (z == 0) {
        *(ushort8*)(Wqt + o) = h0; *(ushort8*)(Wqt + o + 8) = h1;
    } else if (z == 1) {
        *(ushort8*)(Wkt + o) = h0; *(ushort8*)(Wkt + o + 8) = h1;
    } else {
        *(ushort8*)(Wot + o) = h0; *(ushort8*)(Wot + o + 8) = h1;
        if (rem == 128) {   // z==2, bx==0, by==0
            for (int bi = tid; bi < 512; bi += 256) {
                int pp = (bi & 63) * 8 + (bi >> 6);
                bqp[bi] = bq[pp];
                bkp[bi] = bk[pp];
            }
        }
    }
}

// ---------------------------------------------------------------------------
// CSR scan: partial sums (13 blocks) -> final (13 blocks, self-scans bsum)
// ---------------------------------------------------------------------------
#define SCAN_CHUNK 2048

__global__ __launch_bounds__(256) void scan_partial(
    const int* __restrict__ deg, int* __restrict__ bsum, int n)
{
    int base = blockIdx.x * SCAN_CHUNK;
    int t = threadIdx.x;
    int s = 0;
    for (int i = t; i < SCAN_CHUNK; i += 256) {
        int g = base + i;
        s += (g < n) ? deg[g] : 0;
    }
#pragma unroll
    for (int off = 1; off < 64; off <<= 1) s += __shfl_xor(s, off, 64);
    __shared__ int ws[4];
    if ((t & 63) == 0) ws[t >> 6] = s;
    __syncthreads();
    if (t == 0) bsum[blockIdx.x] = ws[0] + ws[1] + ws[2] + ws[3];
}

__global__ __launch_bounds__(256) void scan_final(
    const int* __restrict__ deg, const int* __restrict__ bsum,
    int* __restrict__ rowptr, int* __restrict__ cursor, int n, int nb)
{
    // every block redundantly scans the nb block sums (broadcast loads)
    int boff = 0, total = 0;
    for (int i = 0; i < nb; ++i) {
        int v = bsum[i];
        if (i < (int)blockIdx.x) boff += v;
        total += v;
    }
    int t = threadIdx.x;
    int base = blockIdx.x * SCAN_CHUNK + t * 8;
    int v[8];
    int s = 0;
#pragma unroll
    for (int i = 0; i < 8; ++i) {
        int g = base + i;
        v[i] = (g < n) ? deg[g] : 0;
        s += v[i];
    }
    int lane = t & 63, w = t >> 6;
    int inc = s;
#pragma unroll
    for (int off = 1; off < 64; off <<= 1) {
        int x = __shfl_up(inc, off, 64);
        if (lane >= off) inc += x;
    }
    __shared__ int wsum[4];
    if (lane == 63) wsum[w] = inc;
    __syncthreads();
    int excl = boff + inc - s;
    for (int i = 0; i < w; ++i) excl += wsum[i];
#pragma unroll
    for (int i = 0; i < 8; ++i) {
        int g = base + i;
        if (g < n) { rowptr[g] = excl; cursor[g] = excl; }
        excl += v[i];
    }
    if (blockIdx.x == 0 && t == 0) rowptr[n] = total;
}

__global__ void scatter_kernel(const int* __restrict__ rows, const int* __restrict__ cols,
                               int* __restrict__ cursor, int* __restrict__ colc, int E)
{
    int i = blockIdx.x * 256 + threadIdx.x;
    if (i < E) {
        int pos = atomicAdd(&cursor[rows[i]], 1);
        colc[pos] = cols[i];
    }
}

// ---------------------------------------------------------------------------
// Fused SDDMM + online segment softmax + SpMM. Head-major layout:
// lane l -> head l>>3, dims (l&7)*8..+7. One wave per node, 4 nodes/block.
// 4-edge unroll + depth-4 prefetch. Packed fp16 math: scores via
// v_dot2_f32_f16 (f32 accumulate), aggregation via packed fp16 FMA (fp16 acc,
// defer-max THR=4 so w <= e^4: den <= deg*54.6, acc far from fp16 overflow).
// v == k (source bug): K row loaded for the dot is reused for aggregation.
// ---------------------------------------------------------------------------
__global__ __launch_bounds__(256) void node_agg(
    const u16* __restrict__ Qh, const u16* __restrict__ Kb,
    const int* __restrict__ rowptr, const int* __restrict__ colc,
    u16* __restrict__ aggb, int nN)
{
    int node = blockIdx.x * 4 + (threadIdx.x >> 6);
    int lane = threadIdx.x & 63;
    if (node >= nN) return;
    size_t base = (size_t)node * 512 + lane * 8;

    half8 qv = __builtin_nontemporal_load((const half8*)(Qh + base));
    half2v q2[4];
#pragma unroll
    for (int i = 0; i < 4; ++i) q2[i] = (half2v){qv[2 * i], qv[2 * i + 1]};

    int start = rowptr[node];
    int deg   = rowptr[node + 1] - start;
    const int* cp = colc + start;
    const size_t loff = (size_t)lane * 8;

    float m = -__builtin_inff();
    float den = 0.f;
    half2v acc2[4];
#pragma unroll
    for (int i = 0; i < 4; ++i) acc2[i] = (half2v){(_Float16)0.f, (_Float16)0.f};

    if (deg > 0) {
        const int dl = deg - 1;
        half8 k0 = *(const half8*)(Kb + (size_t)cp[0] * 512 + loff);
        half8 k1 = *(const half8*)(Kb + (size_t)cp[1 < dl ? 1 : dl] * 512 + loff);
        half8 k2 = *(const half8*)(Kb + (size_t)cp[2 < dl ? 2 : dl] * 512 + loff);
        half8 k3 = *(const half8*)(Kb + (size_t)cp[3 < dl ? 3 : dl] * 512 + loff);
        for (int j = 0; j < deg; j += 4) {
            int i4 = j + 4 < dl ? j + 4 : dl;
            int i5 = j + 5 < dl ? j + 5 : dl;
            int i6 = j + 6 < dl ? j + 6 : dl;
            int i7 = j + 7 < dl ? j + 7 : dl;
            half8 n0 = *(const half8*)(Kb + (size_t)cp[i4] * 512 + loff);
            half8 n1 = *(const half8*)(Kb + (size_t)cp[i5] * 512 + loff);
            half8 n2 = *(const half8*)(Kb + (size_t)cp[i6] * 512 + loff);
            half8 n3 = *(const half8*)(Kb + (size_t)cp[i7] * 512 + loff);

            float p0 = 0.f, p1 = 0.f, p2 = 0.f, p3 = 0.f;
#pragma unroll
            for (int i = 0; i < 4; ++i) {
                half2v a = q2[i];
                half2v b0 = (half2v){k0[2 * i], k0[2 * i + 1]};
                half2v b1 = (half2v){k1[2 * i], k1[2 * i + 1]};
                half2v b2 = (half2v){k2[2 * i], k2[2 * i + 1]};
                half2v b3 = (half2v){k3[2 * i], k3[2 * i + 1]};
                p0 = FDOT2(a, b0, p0);
                p1 = FDOT2(a, b1, p1);
                p2 = FDOT2(a, b2, p2);
                p3 = FDOT2(a, b3, p3);
            }
#pragma unroll
            for (int off = 1; off < 8; off <<= 1) {
                p0 += __shfl_xor(p0, off, 64);
                p1 += __shfl_xor(p1, off, 64);
                p2 += __shfl_xor(p2, off, 64);
                p3 += __shfl_xor(p3, off, 64);
            }

            // defer-max (THR=4, fp16-acc-safe): one check per 4-edge group
            float pm = fmaxf(fmaxf(p0, p1), fmaxf(p2, p3));
            if (__any(pm > m + 4.f)) {
                float mn = fmaxf(m, pm);
                float sc = __expf(m - mn);   // first group: exp(-inf)=0
                den *= sc;
                _Float16 sch = (_Float16)sc;
                half2v sc2 = {sch, sch};
#pragma unroll
                for (int i = 0; i < 4; ++i) acc2[i] *= sc2;
                m = mn;
            }
            float w0 = __expf(p0 - m);       // each bounded by e^4
            float w1 = (j + 1 < deg) ? __expf(p1 - m) : 0.f;
            float w2 = (j + 2 < deg) ? __expf(p2 - m) : 0.f;
            float w3 = (j + 3 < deg) ? __expf(p3 - m) : 0.f;
            den += (w0 + w1) + (w2 + w3);
            _Float16 h0 = (_Float16)w0, h1 = (_Float16)w1;
            _Float16 h2 = (_Float16)w2, h3 = (_Float16)w3;
            half2v w02 = {h0, h0}, w12 = {h1, h1}, w22 = {h2, h2}, w32 = {h3, h3};
#pragma unroll
            for (int i = 0; i < 4; ++i) {
                half2v b0 = (half2v){k0[2 * i], k0[2 * i + 1]};
                half2v b1 = (half2v){k1[2 * i], k1[2 * i + 1]};
                half2v b2 = (half2v){k2[2 * i], k2[2 * i + 1]};
                half2v b3 = (half2v){k3[2 * i], k3[2 * i + 1]};
                acc2[i] += w02 * b0;
                acc2[i] += w12 * b1;
                acc2[i] += w22 * b2;
                acc2[i] += w32 * b3;
            }
            k0 = n0; k1 = n1; k2 = n2; k3 = n3;
        }
    }

    float inv = (deg > 0) ? 1.f / den : 0.f;
    ushort8 o;
#pragma unroll
    for (int i = 0; i < 4; ++i) {
        o[2 * i]     = f2h((float)acc2[i][0] * inv);
        o[2 * i + 1] = f2h((float)acc2[i][1] * inv);
    }
    __builtin_nontemporal_store(o, (ushort8*)(aggb + base));
}

// ---------------------------------------------------------------------------
extern "C" void kernel_launch(void* const* d_in, const int* in_sizes, int n_in,
                              void* d_out, int out_size, void* d_ws, size_t ws_size,
                              hipStream_t stream)
{
    const float* h  = (const float*)d_in[0];
    const float* Wq = (const float*)d_in[1];
    const float* bq = (const float*)d_in[2];
    const float* Wk = (const float*)d_in[3];
    const float* bk = (const float*)d_in[4];
    const float* Wo = (const float*)d_in[5];
    const float* bo = (const float*)d_in[6];
    const int* rows = (const int*)d_in[7];
    const int* cols = (const int*)d_in[8];
    float* out = (float*)d_out;

    const int HID = 512;
    const int nN  = in_sizes[0] / HID;              // 25000
    const int E   = in_sizes[7];                    // 400000
    const int nPad = (nN + 127) & ~127;             // 25088
    const int nb = (nN + SCAN_CHUNK - 1) / SCAN_CHUNK;  // 13
    const int nbH = nPad * (HID / 8) / 256;         // conv_h blocks: 6272
    const int nbE = (E + 255) / 256;                // hist blocks: 1563
    const int nMt = nPad / 128;                     // 196 M-tiles
    const int nGrp = (nMt + 7) / 8;                 // 25 XCD groups

    // workspace layout (all 16B-aligned), fp16 throughout (~81 MB)
    char* w = (char*)d_ws;
    u16* Kb  = (u16*)w;  w += (size_t)nPad * HID * 2;  // 25.7 MB
    u16* hh  = (u16*)w;  w += (size_t)nPad * HID * 2;  // 25.7 MB (reused as agg)
    u16* Qh  = (u16*)w;  w += (size_t)nPad * HID * 2;  // 25.7 MB
    u16* Wqt = (u16*)w;  w += 512 * 512 * 2;
    u16* Wkt = (u16*)w;  w += 512 * 512 * 2;
    u16* Wot = (u16*)w;  w += 512 * 512 * 2;
    float* bqp = (float*)w;  w += 512 * 4;
    float* bkp = (float*)w;  w += 512 * 4;
    int* rowptr = (int*)w;   w += (size_t)(nN + 1) * 4;
    int* cursor = (int*)w;   w += (size_t)nN * 4;
    int* deg    = (int*)w;   w += (size_t)nN * 4;
    int* bsum   = (int*)w;   w += 64 * 4;
    int* colc   = (int*)w;   /* E*4 */

    (void)hipMemsetAsync(deg, 0, (size_t)nN * sizeof(int), stream);

    // fused conv_h + hist + conv_w
    prep<<<nbH + nbE + 192, 256, 0, stream>>>(
        h, hh, nN, rows, deg, E, Wq, Wk, Wo, bq, bk,
        Wqt, Wkt, Wot, bqp, bkp, nbH, nbE);

    // CSR: partial scan -> final scan (self-scans block sums) -> scatter
    scan_partial<<<nb, 256, 0, stream>>>(deg, bsum, nN);
    scan_final<<<nb, 256, 0, stream>>>(deg, bsum, rowptr, cursor, nN, nb);
    scatter_kernel<<<(E + 255) / 256, 256, 0, stream>>>(rows, cols, cursor, colc, E);

    // Q + K projections, XCD-grouped mapping (8 sharers per A-tile on one XCD)
    gemm_qk<<<nGrp * 64, 256, 0, stream>>>(
        hh, Wqt, Wkt, bqp, bkp, Qh, Kb, nPad);

    // fused SDDMM + softmax + aggregate -> fp16 agg (overwrites hh)
    node_agg<<<(nN + 3) / 4, 256, 0, stream>>>(Qh, Kb, rowptr, colc, hh, nN);

    // output projection, XCD-grouped (4 sharers per A-tile on one XCD)
    gemm_wo<<<nGrp * 32, 256, 0, stream>>>(hh, Wot, bo, out, nN, nPad);
}

// Round 13
// 233.569 us; speedup vs baseline: 1.1039x; 1.0075x over previous
//
#include <hip/hip_runtime.h>
#include <math.h>

typedef unsigned short u16;
typedef unsigned int u32;
typedef __attribute__((ext_vector_type(8))) _Float16 half8;   // fp16x8
typedef __attribute__((ext_vector_type(2))) _Float16 half2v;  // fp16x2
typedef __attribute__((ext_vector_type(8))) u16 ushort8;
typedef __attribute__((ext_vector_type(4))) float f32x4;

__device__ __forceinline__ u16 f2h(float f) {
    union { u16 u; _Float16 h; } c; c.h = (_Float16)f; return c.u;
}

#if __has_builtin(__builtin_amdgcn_fdot2)
#define FDOT2(a, b, c) __builtin_amdgcn_fdot2((a), (b), (c), false)
#else
#define FDOT2(a, b, c) fmaf((float)(a)[0], (float)(b)[0], \
                        fmaf((float)(a)[1], (float)(b)[1], (c)))
#endif

// async global(16B) -> LDS, per-lane source addr, wave-linear LDS dest
__device__ __forceinline__ void gload16(void* lds, const void* g) {
    __builtin_amdgcn_global_load_lds(
        (const __attribute__((address_space(1))) u32*)g,
        (__attribute__((address_space(3))) u32*)lds,
        16, 0, 0);
}

// ---------------------------------------------------------------------------
// GEMM body, 128m x 256n tile: C[*, colBase..colBase+256) = A @ Bp + bias.
// Bp = B^T panel base (256 rows x 512 k), bias pre-offset to colBase.
// 2-phase double-buffer (proven r9 structure), one barrier per k-step, but
// 2x compute per phase (32 MFMA/wave) -> half the drain-stalls per FLOP.
// LDS tiles [128][32] (A) / [256][32] (B) u16, XOR slot-swizzle (verified
// r6: bank conflicts -> 0): linear gload_lds dest + inverse-swizzled GLOBAL
// source col + swizzled read slot.
// ---------------------------------------------------------------------------
template <int OUTMODE>   // 0: f32 store, 1: fp16 store
__device__ __forceinline__ void gemm_body(
    const u16* A, const u16* Bp, const float* bias, void* Cout, int Mout,
    int m0, int colBase, u16* As0, u16* As1, u16* Bs0, u16* Bs1)
{
    const int tid  = threadIdx.x;
    const int wave = tid >> 6;
    const int lane = tid & 63;
    const int wr = (wave >> 1) * 64;     // 0 / 64
    const int wc = (wave & 1) * 128;     // 0 / 128

    f32x4 acc[4][8];
#pragma unroll
    for (int i = 0; i < 4; ++i)
#pragma unroll
        for (int j = 0; j < 8; ++j) acc[i][j] = (f32x4){0.f, 0.f, 0.f, 0.f};

    const int srow  = lane >> 2;                              // 0..15
    const int scolG = ((lane & 3) ^ ((srow >> 1) & 3)) * 8;   // swizzled global col
    const size_t gOffA = (size_t)(m0 + wave * 32 + srow) * 512 + scolG;
    const size_t gOffB = (size_t)(wave * 64 + srow) * 512 + scolG;
    const int lOffA = wave * 1024 + srow * 32 + (lane & 3) * 8;
    const int lOffB = wave * 2048 + srow * 32 + (lane & 3) * 8;

    const int fR = ((lane & 15) >> 1) & 3;
    const int paOff = (wr + (lane & 15)) * 32 + ((lane >> 4) ^ fR) * 8;
    const int pbOff = (wc + (lane & 15)) * 32 + ((lane >> 4) ^ fR) * 8;

    auto STAGE = [&](u16* sa, u16* sb, int ko) {
        gload16(sa + lOffA,        A  + gOffA + ko);
        gload16(sa + lOffA + 512,  A  + gOffA + ko + 16 * 512);
        gload16(sb + lOffB,        Bp + gOffB + ko);
        gload16(sb + lOffB + 512,  Bp + gOffB + ko + 16 * 512);
        gload16(sb + lOffB + 1024, Bp + gOffB + ko + 32 * 512);
        gload16(sb + lOffB + 1536, Bp + gOffB + ko + 48 * 512);
    };
    auto COMPUTE = [&](const u16* sa, const u16* sb) {
        half8 af[4], bf[8];
#pragma unroll
        for (int i = 0; i < 4; ++i) af[i] = *(const half8*)(sa + paOff + i * 512);
#pragma unroll
        for (int j = 0; j < 8; ++j) bf[j] = *(const half8*)(sb + pbOff + j * 512);
#pragma unroll
        for (int i = 0; i < 4; ++i)
#pragma unroll
            for (int j = 0; j < 8; ++j)
                acc[i][j] = __builtin_amdgcn_mfma_f32_16x16x32_f16(
                    af[i], bf[j], acc[i][j], 0, 0, 0);
    };

    STAGE(As0, Bs0, 0);
    __syncthreads();
#pragma unroll
    for (int kt = 0; kt < 16; kt += 2) {
        STAGE(As1, Bs1, (kt + 1) * 32);
        COMPUTE(As0, Bs0);
        __syncthreads();
        if (kt + 2 < 16) STAGE(As0, Bs0, (kt + 2) * 32);
        COMPUTE(As1, Bs1);
        __syncthreads();
    }

    const int ccolL = wc + (lane & 15);              // 0..255 within panel
    const int crow0 = m0 + wr + (lane >> 4) * 4;
#pragma unroll
    for (int j = 0; j < 8; ++j) {
        const float b = bias[ccolL + j * 16];
        const int col = colBase + ccolL + j * 16;
#pragma unroll
        for (int i = 0; i < 4; ++i) {
#pragma unroll
            for (int r = 0; r < 4; ++r) {
                int row = crow0 + i * 16 + r;
                if (row < Mout) {
                    float v = acc[i][j][r] + b;
                    size_t off = (size_t)row * 512 + col;
                    if (OUTMODE == 0) ((float*)Cout)[off] = v;
                    else              ((u16*)Cout)[off] = f2h(v);
                }
            }
        }
    }
}

// Q + K projections in ONE dispatch, XCD-grouped block mapping: the 4 blocks
// sharing an A M-tile (2x256-wide panels per output, Q and K) get bids
// bid = 32*(m/8) + 8*s + (m%8)  =>  same bid%8 (same XCD, round-robin) and
// adjacent dispatch order -> A-tile read once from HBM, 3x from that XCD L2.
__global__ __launch_bounds__(256) void gemm_qk(
    const u16* __restrict__ hh, const u16* __restrict__ Wqt,
    const u16* __restrict__ Wkt, const float* __restrict__ bqp,
    const float* __restrict__ bkp, u16* __restrict__ Qh,
    u16* __restrict__ Kb, int nPad)
{
    const int bid = blockIdx.x;
    const int m = (bid >> 5) * 8 + (bid & 7);
    const int s = (bid >> 3) & 3;          // 0..3 over 1024 combined cols
    if (m >= nPad / 128) return;
    const int z = s >> 1;                  // 0: Q, 1: K
    const int nloc = (s & 1) * 256;        // panel within the 512-wide output

    __shared__ __align__(16) u16 As0[4096], As1[4096], Bs0[8192], Bs1[8192];
    const u16* Bp = (z ? Wkt : Wqt) + (size_t)nloc * 512;
    const float* bp = (z ? bkp : bqp) + nloc;
    u16* out = z ? Kb : Qh;
    gemm_body<1>(hh, Bp, bp, out, nPad, m * 128, nloc, As0, As1, Bs0, Bs1);
}

// Wo projection, same XCD-grouping with 2 sharers per A M-tile:
// bid = 16*(m/8) + 8*s + (m%8), s in {0,1}.
__global__ __launch_bounds__(256) void gemm_wo(
    const u16* __restrict__ A, const u16* __restrict__ Wot,
    const float* __restrict__ bo, float* __restrict__ C, int Mout, int nPad)
{
    const int bid = blockIdx.x;
    const int m = (bid >> 4) * 8 + (bid & 7);
    const int s = (bid >> 3) & 1;
    if (m >= nPad / 128) return;
    const int nloc = s * 256;

    __shared__ __align__(16) u16 As0[4096], As1[4096], Bs0[8192], Bs1[8192];
    gemm_body<0>(A, Wot + (size_t)nloc * 512, bo + nloc, C, Mout,
                 m * 128, nloc, As0, As1, Bs0, Bs1);
}

// ---------------------------------------------------------------------------
// prep: fused conv_h (h f32 -> fp16, pad zeroed) + hist + conv_w.
// Grid partition: [0,nbH) conv_h, [nbH,nbH+nbE) hist, [nbH+nbE,+192) conv_w.
// ---------------------------------------------------------------------------
__global__ __launch_bounds__(256) void prep(
    const float* __restrict__ h, u16* __restrict__ hh, int nN,
    const int* __restrict__ rows, int* __restrict__ deg, int E,
    const float* __restrict__ Wq, const float* __restrict__ Wk,
    const float* __restrict__ Wo, const float* __restrict__ bq,
    const float* __restrict__ bk,
    u16* __restrict__ Wqt, u16* __restrict__ Wkt, u16* __restrict__ Wot,
    float* __restrict__ bqp, float* __restrict__ bkp,
    int nbH, int nbE)
{
    __shared__ float T[64][65];
    const int tid = threadIdx.x;
    const int b = blockIdx.x;

    if (b < nbH) {
        // ---- conv_h ----
        int t = b * 256 + tid;
        size_t e = (size_t)t * 8;
        int row = (int)(e >> 9);
        ushort8 o;
        if (row < nN) {
            f32x4 a = *(const f32x4*)(h + e);
            f32x4 bb = *(const f32x4*)(h + e + 4);
            float x[8] = {a.x, a.y, a.z, a.w, bb.x, bb.y, bb.z, bb.w};
#pragma unroll
            for (int i = 0; i < 8; ++i) o[i] = f2h(x[i]);
        } else {
            o = (ushort8){0,0,0,0,0,0,0,0};
        }
        *(ushort8*)(hh + e) = o;
        return;
    }
    if (b < nbH + nbE) {
        // ---- hist ----
        int i = (b - nbH) * 256 + tid;
        if (i < E) atomicAdd(&deg[rows[i]], 1);
        return;
    }
    // ---- conv_w ----  (192 blocks: z = rem>>6, by = (rem&63)>>3, bx = rem&7)
    int rem = b - nbH - nbE;
    const int z = rem >> 6;
    const int X = (rem & 7) * 64;
    const int Y = ((rem >> 3) & 7) * 64;

    const int r4 = tid >> 4;
    const int c4 = (tid & 15) * 4;
    if (z < 2) {
        const float* W = z ? Wk : Wq;
#pragma unroll
        for (int rr = 0; rr < 64; rr += 16) {
            f32x4 v = *(const f32x4*)(W + (size_t)(X + rr + r4) * 512 + Y + c4);
            T[rr + r4][c4 + 0] = v.x; T[rr + r4][c4 + 1] = v.y;
            T[rr + r4][c4 + 2] = v.z; T[rr + r4][c4 + 3] = v.w;
        }
    } else {
#pragma unroll
        for (int rr = 0; rr < 64; rr += 16) {
            int p2 = (rr + r4) * 8 + (X >> 6);   // perm(X + rr + r4)
            f32x4 v = *(const f32x4*)(Wo + (size_t)p2 * 512 + Y + c4);
            T[rr + r4][c4 + 0] = v.x; T[rr + r4][c4 + 1] = v.y;
            T[rr + r4][c4 + 2] = v.z; T[rr + r4][c4 + 3] = v.w;
        }
    }
    __syncthreads();

    const int cc = tid >> 2;
    const int ks = (tid & 3) * 16;
    const int pc = Y + cc;
    const int ro = (z < 2) ? ((pc & 7) * 64 + (pc >> 3)) : pc;
    ushort8 h0, h1;
#pragma unroll
    for (int t = 0; t < 8; ++t) {
        h0[t] = f2h(T[ks + t][cc]);
        h1[t] = f2h(T[ks + 8 + t][cc]);
    }
    size_t o = (size_t)ro * 512 + X + ks;
    if (z == 0) {
        *(ushort8*)(Wqt + o) = h0; *(ushort8*)(Wqt + o + 8) = h1;
    } else if (z == 1) {
        *(ushort8*)(Wkt + o) = h0; *(ushort8*)(Wkt + o + 8) = h1;
    } else {
        *(ushort8*)(Wot + o) = h0; *(ushort8*)(Wot + o + 8) = h1;
        if (rem == 128) {   // z==2, bx==0, by==0
            for (int bi = tid; bi < 512; bi += 256) {
                int pp = (bi & 63) * 8 + (bi >> 6);
                bqp[bi] = bq[pp];
                bkp[bi] = bk[pp];
            }
        }
    }
}

// ---------------------------------------------------------------------------
// CSR scan: partial sums (13 blocks) -> final (13 blocks, self-scans bsum)
// ---------------------------------------------------------------------------
#define SCAN_CHUNK 2048

__global__ __launch_bounds__(256) void scan_partial(
    const int* __restrict__ deg, int* __restrict__ bsum, int n)
{
    int base = blockIdx.x * SCAN_CHUNK;
    int t = threadIdx.x;
    int s = 0;
    for (int i = t; i < SCAN_CHUNK; i += 256) {
        int g = base + i;
        s += (g < n) ? deg[g] : 0;
    }
#pragma unroll
    for (int off = 1; off < 64; off <<= 1) s += __shfl_xor(s, off, 64);
    __shared__ int ws[4];
    if ((t & 63) == 0) ws[t >> 6] = s;
    __syncthreads();
    if (t == 0) bsum[blockIdx.x] = ws[0] + ws[1] + ws[2] + ws[3];
}

__global__ __launch_bounds__(256) void scan_final(
    const int* __restrict__ deg, const int* __restrict__ bsum,
    int* __restrict__ rowptr, int* __restrict__ cursor, int n, int nb)
{
    // every block redundantly scans the nb block sums (broadcast loads)
    int boff = 0, total = 0;
    for (int i = 0; i < nb; ++i) {
        int v = bsum[i];
        if (i < (int)blockIdx.x) boff += v;
        total += v;
    }
    int t = threadIdx.x;
    int base = blockIdx.x * SCAN_CHUNK + t * 8;
    int v[8];
    int s = 0;
#pragma unroll
    for (int i = 0; i < 8; ++i) {
        int g = base + i;
        v[i] = (g < n) ? deg[g] : 0;
        s += v[i];
    }
    int lane = t & 63, w = t >> 6;
    int inc = s;
#pragma unroll
    for (int off = 1; off < 64; off <<= 1) {
        int x = __shfl_up(inc, off, 64);
        if (lane >= off) inc += x;
    }
    __shared__ int wsum[4];
    if (lane == 63) wsum[w] = inc;
    __syncthreads();
    int excl = boff + inc - s;
    for (int i = 0; i < w; ++i) excl += wsum[i];
#pragma unroll
    for (int i = 0; i < 8; ++i) {
        int g = base + i;
        if (g < n) { rowptr[g] = excl; cursor[g] = excl; }
        excl += v[i];
    }
    if (blockIdx.x == 0 && t == 0) rowptr[n] = total;
}

__global__ void scatter_kernel(const int* __restrict__ rows, const int* __restrict__ cols,
                               int* __restrict__ cursor, int* __restrict__ colc, int E)
{
    int i = blockIdx.x * 256 + threadIdx.x;
    if (i < E) {
        int pos = atomicAdd(&cursor[rows[i]], 1);
        colc[pos] = cols[i];
    }
}

// ---------------------------------------------------------------------------
// Fused SDDMM + online segment softmax + SpMM. Head-major layout:
// lane l -> head l>>3, dims (l&7)*8..+7. One wave per node, 4 nodes/block.
// 8-edge unroll + depth-8 prefetch (8 KB in flight/wave). Packed fp16 math:
// scores via v_dot2_f32_f16 (f32 accum), aggregation packed fp16 (defer-max
// THR=4: w <= e^4, den <= deg*54.6, acc far from fp16 overflow).
// v == k (source bug): K row loaded for the dot is reused for aggregation.
// ---------------------------------------------------------------------------
__global__ __launch_bounds__(256) void node_agg(
    const u16* __restrict__ Qh, const u16* __restrict__ Kb,
    const int* __restrict__ rowptr, const int* __restrict__ colc,
    u16* __restrict__ aggb, int nN)
{
    int node = blockIdx.x * 4 + (threadIdx.x >> 6);
    int lane = threadIdx.x & 63;
    if (node >= nN) return;
    size_t base = (size_t)node * 512 + lane * 8;

    half8 qv = __builtin_nontemporal_load((const half8*)(Qh + base));
    half2v q2[4];
#pragma unroll
    for (int i = 0; i < 4; ++i) q2[i] = (half2v){qv[2 * i], qv[2 * i + 1]};

    int start = rowptr[node];
    int deg   = rowptr[node + 1] - start;
    const int* cp = colc + start;
    const size_t loff = (size_t)lane * 8;

    float m = -__builtin_inff();
    float den = 0.f;
    half2v acc2[4];
#pragma unroll
    for (int i = 0; i < 4; ++i) acc2[i] = (half2v){(_Float16)0.f, (_Float16)0.f};

    if (deg > 0) {
        const int dl = deg - 1;
        half8 k[8];
#pragma unroll
        for (int t = 0; t < 8; ++t) {
            int it = t < dl ? t : dl;
            k[t] = *(const half8*)(Kb + (size_t)cp[it] * 512 + loff);
        }
        for (int j = 0; j < deg; j += 8) {
            half8 nx[8];
#pragma unroll
            for (int t = 0; t < 8; ++t) {
                int it = j + 8 + t < dl ? j + 8 + t : dl;
                nx[t] = *(const half8*)(Kb + (size_t)cp[it] * 512 + loff);
            }

            float p[8];
#pragma unroll
            for (int t = 0; t < 8; ++t) {
                float s = 0.f;
#pragma unroll
                for (int i = 0; i < 4; ++i) {
                    half2v bb = (half2v){k[t][2 * i], k[t][2 * i + 1]};
                    s = FDOT2(q2[i], bb, s);
                }
                p[t] = s;
            }
#pragma unroll
            for (int off = 1; off < 8; off <<= 1) {
#pragma unroll
                for (int t = 0; t < 8; ++t) p[t] += __shfl_xor(p[t], off, 64);
            }

            // defer-max (THR=4, fp16-acc-safe): one check per 8-edge group
            float pm = p[0];
#pragma unroll
            for (int t = 1; t < 8; ++t) pm = fmaxf(pm, p[t]);
            if (__any(pm > m + 4.f)) {
                float mn = fmaxf(m, pm);
                float sc = __expf(m - mn);   // first group: exp(-inf)=0
                den *= sc;
                _Float16 sch = (_Float16)sc;
                half2v sc2 = {sch, sch};
#pragma unroll
                for (int i = 0; i < 4; ++i) acc2[i] *= sc2;
                m = mn;
            }
#pragma unroll
            for (int t = 0; t < 8; ++t) {
                float w = (j + t < deg) ? __expf(p[t] - m) : 0.f;  // <= e^4
                den += w;
                _Float16 wh = (_Float16)w;
                half2v w2 = {wh, wh};
#pragma unroll
                for (int i = 0; i < 4; ++i) {
                    half2v bb = (half2v){k[t][2 * i], k[t][2 * i + 1]};
                    acc2[i] += w2 * bb;
                }
            }
#pragma unroll
            for (int t = 0; t < 8; ++t) k[t] = nx[t];
        }
    }

    float inv = (deg > 0) ? 1.f / den : 0.f;
    ushort8 o;
#pragma unroll
    for (int i = 0; i < 4; ++i) {
        o[2 * i]     = f2h((float)acc2[i][0] * inv);
        o[2 * i + 1] = f2h((float)acc2[i][1] * inv);
    }
    __builtin_nontemporal_store(o, (ushort8*)(aggb + base));
}

// ---------------------------------------------------------------------------
extern "C" void kernel_launch(void* const* d_in, const int* in_sizes, int n_in,
                              void* d_out, int out_size, void* d_ws, size_t ws_size,
                              hipStream_t stream)
{
    const float* h  = (const float*)d_in[0];
    const float* Wq = (const float*)d_in[1];
    const float* bq = (const float*)d_in[2];
    const float* Wk = (const float*)d_in[3];
    const float* bk = (const float*)d_in[4];
    const float* Wo = (const float*)d_in[5];
    const float* bo = (const float*)d_in[6];
    const int* rows = (const int*)d_in[7];
    const int* cols = (const int*)d_in[8];
    float* out = (float*)d_out;

    const int HID = 512;
    const int nN  = in_sizes[0] / HID;              // 25000
    const int E   = in_sizes[7];                    // 400000
    const int nPad = (nN + 127) & ~127;             // 25088
    const int nb = (nN + SCAN_CHUNK - 1) / SCAN_CHUNK;  // 13
    const int nbH = nPad * (HID / 8) / 256;         // conv_h blocks: 6272
    const int nbE = (E + 255) / 256;                // hist blocks: 1563
    const int nMt = nPad / 128;                     // 196 M-tiles
    const int nGrp = (nMt + 7) / 8;                 // 25 XCD groups

    // workspace layout (all 16B-aligned), fp16 throughout (~81 MB)
    char* w = (char*)d_ws;
    u16* Kb  = (u16*)w;  w += (size_t)nPad * HID * 2;  // 25.7 MB
    u16* hh  = (u16*)w;  w += (size_t)nPad * HID * 2;  // 25.7 MB (reused as agg)
    u16* Qh  = (u16*)w;  w += (size_t)nPad * HID * 2;  // 25.7 MB
    u16* Wqt = (u16*)w;  w += 512 * 512 * 2;
    u16* Wkt = (u16*)w;  w += 512 * 512 * 2;
    u16* Wot = (u16*)w;  w += 512 * 512 * 2;
    float* bqp = (float*)w;  w += 512 * 4;
    float* bkp = (float*)w;  w += 512 * 4;
    int* rowptr = (int*)w;   w += (size_t)(nN + 1) * 4;
    int* cursor = (int*)w;   w += (size_t)nN * 4;
    int* deg    = (int*)w;   w += (size_t)nN * 4;
    int* bsum   = (int*)w;   w += 64 * 4;
    int* colc   = (int*)w;   /* E*4 */

    (void)hipMemsetAsync(deg, 0, (size_t)nN * sizeof(int), stream);

    // fused conv_h + hist + conv_w
    prep<<<nbH + nbE + 192, 256, 0, stream>>>(
        h, hh, nN, rows, deg, E, Wq, Wk, Wo, bq, bk,
        Wqt, Wkt, Wot, bqp, bkp, nbH, nbE);

    // CSR: partial scan -> final scan (self-scans block sums) -> scatter
    scan_partial<<<nb, 256, 0, stream>>>(deg, bsum, nN);
    scan_final<<<nb, 256, 0, stream>>>(deg, bsum, rowptr, cursor, nN, nb);
    scatter_kernel<<<(E + 255) / 256, 256, 0, stream>>>(rows, cols, cursor, colc, E);

    // Q + K projections, 128x256 tiles, XCD-grouped (4 sharers per A-tile)
    gemm_qk<<<nGrp * 32, 256, 0, stream>>>(
        hh, Wqt, Wkt, bqp, bkp, Qh, Kb, nPad);

    // fused SDDMM + softmax + aggregate -> fp16 agg (overwrites hh)
    node_agg<<<(nN + 3) / 4, 256, 0, stream>>>(Qh, Kb, rowptr, colc, hh, nN);

    // output projection, 128x256 tiles, XCD-grouped (2 sharers per A-tile)
    gemm_wo<<<nGrp * 16, 256, 0, stream>>>(hh, Wot, bo, out, nN, nPad);
}